// Round 4
// baseline (66.533 us; speedup 1.0000x reference)
//
#include <hip/hip_runtime.h>

// Fused static-genome evaluation.
// Input dict order: loss(1), prev_loss(1), weights(24), p0..p7 (2048*4096 f32 each).
// Outputs: nodes 18,19,20,21 concatenated -> 4 * 8388608 f32.
//
// out0 = w16*w0*p0 + w16*w1*p1 + w17*w2*p2 + w17*w3*p3
// out1 = w18*w4*p4 + w18*w5*p5 + w19*w6*p6 + w19*w7*p7
// out2 = w20*w8*p0 + w21*w10*p1 + w21*w11*p6 + w20*w9*p7
// out3 = w22*w12*p2 + w23*w14*p3 + w23*w15*p4 + w22*w13*p5
//
// R4: 2 float4 per thread (distant halves -> every load instruction stays
// unit-stride coalesced), all 16 loads issued before any use for 2x MLP.
// Nontemporal stores keep output stream from evicting L3-resident inputs.

typedef float fx4 __attribute__((ext_vector_type(4)));

__global__ __launch_bounds__(256) void genome_fused_kernel(
    const float* __restrict__ w,
    const float* __restrict__ p0, const float* __restrict__ p1,
    const float* __restrict__ p2, const float* __restrict__ p3,
    const float* __restrict__ p4, const float* __restrict__ p5,
    const float* __restrict__ p6, const float* __restrict__ p7,
    float* __restrict__ out, int half, int n)
{
    const int i = blockIdx.x * 256 + threadIdx.x;
    if (i >= half) return;
    const int j = i + half;

    const fx4* __restrict__ v0 = (const fx4*)p0;
    const fx4* __restrict__ v1 = (const fx4*)p1;
    const fx4* __restrict__ v2 = (const fx4*)p2;
    const fx4* __restrict__ v3 = (const fx4*)p3;
    const fx4* __restrict__ v4 = (const fx4*)p4;
    const fx4* __restrict__ v5 = (const fx4*)p5;
    const fx4* __restrict__ v6 = (const fx4*)p6;
    const fx4* __restrict__ v7 = (const fx4*)p7;

    // Issue all 16 independent loads before any use (2x MLP vs R3).
    fx4 a0 = v0[i]; fx4 b0 = v0[j];
    fx4 a1 = v1[i]; fx4 b1 = v1[j];
    fx4 a2 = v2[i]; fx4 b2 = v2[j];
    fx4 a3 = v3[i]; fx4 b3 = v3[j];
    fx4 a4 = v4[i]; fx4 b4 = v4[j];
    fx4 a5 = v5[i]; fx4 b5 = v5[j];
    fx4 a6 = v6[i]; fx4 b6 = v6[j];
    fx4 a7 = v7[i]; fx4 b7 = v7[j];

    // Coefficients (wave-uniform scalar loads; overlap with vector loads)
    const float c00 = w[16] * w[0];
    const float c01 = w[16] * w[1];
    const float c02 = w[17] * w[2];
    const float c03 = w[17] * w[3];

    const float c14 = w[18] * w[4];
    const float c15 = w[18] * w[5];
    const float c16 = w[19] * w[6];
    const float c17 = w[19] * w[7];

    const float c20 = w[20] * w[8];
    const float c27 = w[20] * w[9];
    const float c21 = w[21] * w[10];
    const float c26 = w[21] * w[11];

    const float c32 = w[22] * w[12];
    const float c35 = w[22] * w[13];
    const float c33 = w[23] * w[14];
    const float c34 = w[23] * w[15];

    fx4 r0 = c00*a0 + c01*a1 + c02*a2 + c03*a3;
    fx4 r1 = c14*a4 + c15*a5 + c16*a6 + c17*a7;
    fx4 r2 = c20*a0 + c21*a1 + c26*a6 + c27*a7;
    fx4 r3 = c32*a2 + c33*a3 + c34*a4 + c35*a5;

    fx4 s0 = c00*b0 + c01*b1 + c02*b2 + c03*b3;
    fx4 s1 = c14*b4 + c15*b5 + c16*b6 + c17*b7;
    fx4 s2 = c20*b0 + c21*b1 + c26*b6 + c27*b7;
    fx4 s3 = c32*b2 + c33*b3 + c34*b4 + c35*b5;

    fx4* __restrict__ o0 = (fx4*)out;
    fx4* __restrict__ o1 = (fx4*)(out + (size_t)n);
    fx4* __restrict__ o2 = (fx4*)(out + 2 * (size_t)n);
    fx4* __restrict__ o3 = (fx4*)(out + 3 * (size_t)n);

    __builtin_nontemporal_store(r0, &o0[i]);
    __builtin_nontemporal_store(r1, &o1[i]);
    __builtin_nontemporal_store(r2, &o2[i]);
    __builtin_nontemporal_store(r3, &o3[i]);
    __builtin_nontemporal_store(s0, &o0[j]);
    __builtin_nontemporal_store(s1, &o1[j]);
    __builtin_nontemporal_store(s2, &o2[j]);
    __builtin_nontemporal_store(s3, &o3[j]);
}

extern "C" void kernel_launch(void* const* d_in, const int* in_sizes, int n_in,
                              void* d_out, int out_size, void* d_ws, size_t ws_size,
                              hipStream_t stream) {
    // d_in order: 0=loss, 1=prev_loss, 2=weights[24], 3..10 = p0..p7
    const float* w  = (const float*)d_in[2];
    const float* p0 = (const float*)d_in[3];
    const float* p1 = (const float*)d_in[4];
    const float* p2 = (const float*)d_in[5];
    const float* p3 = (const float*)d_in[6];
    const float* p4 = (const float*)d_in[7];
    const float* p5 = (const float*)d_in[8];
    const float* p6 = (const float*)d_in[9];
    const float* p7 = (const float*)d_in[10];

    const int n    = in_sizes[3];    // 2048*4096 = 8388608
    const int n4   = n / 4;          // float4 chunks (2097152)
    const int half = n4 / 2;         // 1048576

    const int block = 256;
    const int grid = (half + block - 1) / block;  // 4096 blocks, 2 float4/thread

    genome_fused_kernel<<<grid, block, 0, stream>>>(
        w, p0, p1, p2, p3, p4, p5, p6, p7, (float*)d_out, half, n);
}